// Round 5
// baseline (252.256 us; speedup 1.0000x reference)
//
#include <hip/hip_runtime.h>
#include <math.h>

// sources: [4][32][512][512] fp32, kernels: [12][3][3] fp32, out: same as sources
// out_i = s_i - sum_j [ conv(s_j, kc_ij) + conv((s_j^0.5 * s_i)^(2/3), ki_ij) ]
//
// Identity: a = v^(1/3) => s = a^3, (s_j^0.5 * s_i)^(2/3) = a_j * a_i^2.
// Stage only a in LDS; conv is multiply/FMA only; edge sweep (0,1),(1,2),(2,3).
//
// ROUND-5 CHANGES:
//  (a) Side halo array sH[ch][row][33]: window cols 4tx+3 / 4tx+8 were 8-way
//      bank-conflicted b32 reads (stride 72 = 8 mod 32 keeps 64 lanes on 8
//      banks; ANY stride = 0 mod 4 does). sH stride 33 = 1 mod 32 gives
//      bank = row+tx -> <=4-way. Values identical; conv math untouched.
//  (b) 2 images per block + register prefetch: issue image-2 float4 loads
//      before the stage->conv barrier, consume after conv-1. Barriers are
//      raw s_barrier + lgkmcnt(0) (NOT __syncthreads: that drains vmcnt(0)
//      and would serialize the prefetch; only LDS visibility is required).
//
// HISTORY (do not regress):
//  - launch_bounds (256,8)/(256,4): VGPR cap -> spills (WRITE_SIZE >> 131 MB
//    tripwire). Leave unbounded.
//  - scalar staging loads: Little's-law capped whole kernel at ~250 us.
//    Keep batched float4 staging.

#define NCH  4
#define NIMG 32
#define HH   512
#define WW   512

#define TW   64
#define TH   16
#define HTW  72            // main LDS row stride (dwords); col k = global tile_x+k-4
#define HSW  33            // side halo row stride (dwords); 33 % 32 == 1
#define HTH  18
#define NTASK (NCH * HTH)  // 72 row-channel staging tasks

#if __has_builtin(__builtin_amdgcn_exp2f)
#define EXP2(x) __builtin_amdgcn_exp2f(x)
#else
#define EXP2(x) exp2f(x)
#endif
#if __has_builtin(__builtin_amdgcn_logf)
#define LOG2(x) __builtin_amdgcn_logf(x)
#else
#define LOG2(x) __log2f(x)
#endif

// Barrier with LDS-visibility only: do NOT let the compiler drain vmcnt
// (prefetched global loads stay in flight across the barrier).
#define BAR_LDS() do {                                          \
    asm volatile("s_waitcnt lgkmcnt(0)" ::: "memory");          \
    __builtin_amdgcn_s_barrier();                               \
    asm volatile("" ::: "memory");                              \
} while (0)

__device__ __forceinline__ float cbrtfast(float v) {
    return EXP2(0.33333334f * LOG2(v));   // v=0 -> -inf -> 0 (correct zero-pad)
}

// Window = LDS cols tx4+3 .. tx4+8. Middle 4 from aligned b128; the two edge
// values come from the conflict-cheap side array (w0 = sH[row][tx],
// w5 = sH[row][16+tx]).
__device__ __forceinline__ void load_row6(const float* __restrict__ row,
                                          const float* __restrict__ hrow,
                                          int tx, float w[6]) {
    const float4 m = *(const float4*)(row + 4);
    w[0] = hrow[tx];
    w[1] = m.x; w[2] = m.y; w[3] = m.z; w[4] = m.w;
    w[5] = hrow[16 + tx];
}

// Edge between channels x and y = x+1 (a-values in Sx/Hx, Sy/Hy).
//   accX += conv(a_y^3, ker[KCX]) + conv(a_x^2 * a_y, ker[KIX])   (i=x, j=y)
//   accY += conv(a_x^3, ker[KCY]) + conv(a_y^2 * a_x, ker[KIY])   (i=y, j=x)
template<int KCX, int KIX, int KCY, int KIY, bool CAPY>
__device__ __forceinline__ void edge_conv(
    const float (*Sx)[HTW], const float (*Sy)[HTW],
    const float (*Hx)[HSW], const float (*Hy)[HSW],
    int ty, int tx, int tx4, const float* __restrict__ ker,
    float accX[4], float accY[4], float cx[4], float cy[4])
{
    #pragma unroll
    for (int r = 0; r < 3; ++r) {
        float ax[6], ay[6];
        load_row6(&Sx[ty + r][tx4], Hx[ty + r], tx, ax);
        load_row6(&Sy[ty + r][tx4], Hy[ty + r], tx, ay);
        if (r == 1) {
            #pragma unroll
            for (int q = 0; q < 4; ++q) cx[q] = ax[q + 1];
            if (CAPY) {
                #pragma unroll
                for (int q = 0; q < 4; ++q) cy[q] = ay[q + 1];
            }
        }
        float ay2[6];
        #pragma unroll
        for (int q = 0; q < 6; ++q) ay2[q] = ay[q] * ay[q];

        // i=x (neighbor j=y): raw_y = ay^3, inter = ax^2 * ay
        {
            float w[6], t[6];
            #pragma unroll
            for (int q = 0; q < 6; ++q) {
                w[q] = ay2[q] * ay[q];
                t[q] = (ax[q] * ax[q]) * ay[q];
            }
            #pragma unroll
            for (int q = 0; q < 4; ++q) {
                float s = accX[q];
                #pragma unroll
                for (int dx = 0; dx < 3; ++dx) {
                    s = fmaf(w[q + dx], ker[KCX * 9 + r * 3 + dx], s);
                    s = fmaf(t[q + dx], ker[KIX * 9 + r * 3 + dx], s);
                }
                accX[q] = s;
            }
        }
        // i=y (neighbor j=x): raw_x = ax^3, inter = ay^2 * ax
        {
            float w[6], t[6];
            #pragma unroll
            for (int q = 0; q < 6; ++q) {
                w[q] = (ax[q] * ax[q]) * ax[q];
                t[q] = ay2[q] * ax[q];
            }
            #pragma unroll
            for (int q = 0; q < 4; ++q) {
                float s = accY[q];
                #pragma unroll
                for (int dx = 0; dx < 3; ++dx) {
                    s = fmaf(w[q + dx], ker[KCY * 9 + r * 3 + dx], s);
                    s = fmaf(t[q + dx], ker[KIY * 9 + r * 3 + dx], s);
                }
                accY[q] = s;
            }
        }
    }
}

__device__ __forceinline__ void store_out(float* __restrict__ p,
                                          const float c[4], const float a[4]) {
    float4 o;
    o.x = c[0] * c[0] * c[0] - a[0];
    o.y = c[1] * c[1] * c[1] - a[1];
    o.z = c[2] * c[2] * c[2] - a[2];
    o.w = c[3] * c[3] * c[3] - a[3];
    *(float4*)p = o;
}

struct Stage {
    float4 vv[5];
    float  hv[5];
};

// Issue all global loads for one image's tile (batched, 80+ B/lane in flight).
__device__ __forceinline__ void stage_load(
    const float* __restrict__ src, int n, int tile_x, int tile_y,
    int g, int L, size_t plane, Stage& st)
{
    #pragma unroll
    for (int it = 0; it < 5; ++it) {
        const int t   = g + it * 16;
        const int c   = t / HTH;
        const int row = t - c * HTH;
        const int gy  = tile_y - 1 + row;
        float4 v = make_float4(0.f, 0.f, 0.f, 0.f);
        float  h = 0.f;
        if (t < NTASK && (unsigned)gy < HH) {
            const float* rp = src + ((size_t)c * NIMG + n) * plane
                                  + (size_t)gy * WW;
            v = *(const float4*)(rp + tile_x + 4 * L);
            if (L == 0 && tile_x > 0)       h = rp[tile_x - 1];
            if (L == 1 && tile_x + TW < WW) h = rp[tile_x + TW];
        }
        st.vv[it] = v;
        st.hv[it] = h;
    }
}

// cbrt + LDS writes (main b128 + side halo b32s).
__device__ __forceinline__ void stage_write(
    float (*sA)[HTH][HTW], float (*sH)[HTH][HSW],
    int g, int L, const Stage& st)
{
    #pragma unroll
    for (int it = 0; it < 5; ++it) {
        const int t = g + it * 16;
        if (t < NTASK) {
            const int c   = t / HTH;
            const int row = t - c * HTH;
            float4 a;
            a.x = cbrtfast(st.vv[it].x);
            a.y = cbrtfast(st.vv[it].y);
            a.z = cbrtfast(st.vv[it].z);
            a.w = cbrtfast(st.vv[it].w);
            const float ah = cbrtfast(st.hv[it]);
            *(float4*)&sA[c][row][4 + 4 * L] = a;   // 16B-aligned ds_write
            // side array: w0[tx] = col 4tx+3 (lane tx-1 slot3), w5[tx] = col
            // 4tx+8 (lane tx+1 slot0); tile-edge cases come from halo loads.
            if (L <= 14) sH[c][row][L + 1]  = a.w;
            if (L >= 1)  sH[c][row][15 + L] = a.x;   // = 16 + (L-1)
            if (L == 0)  sH[c][row][0]      = ah;    // left halo -> w0[tx=0]
            if (L == 1)  sH[c][row][31]     = ah;    // right halo -> w5[tx=15]
        }
    }
}

__device__ __forceinline__ void conv_image(
    const float (*sA)[HTH][HTW], const float (*sH)[HTH][HSW],
    int ty, int tx, int tx4, const float* __restrict__ ker,
    float* __restrict__ outp, size_t cstride)
{
    float accL[4] = {0.f, 0.f, 0.f, 0.f};
    float accH[4] = {0.f, 0.f, 0.f, 0.f};
    float cA[4], cB[4];

    // edge (0,1): i=0 gets kc=0,ki=1 ; i=1 gets kc=2,ki=3
    edge_conv<0, 1, 2, 3, false>(sA[0], sA[1], sH[0], sH[1],
                                 ty, tx, tx4, ker, accL, accH, cA, cB);
    store_out(outp, cA, accL);                       // channel 0 complete

    #pragma unroll
    for (int q = 0; q < 4; ++q) { accL[q] = accH[q]; accH[q] = 0.f; }

    // edge (1,2): i=1 gets kc=4,ki=5 ; i=2 gets kc=6,ki=7
    edge_conv<4, 5, 6, 7, false>(sA[1], sA[2], sH[1], sH[2],
                                 ty, tx, tx4, ker, accL, accH, cA, cB);
    store_out(outp + cstride, cA, accL);             // channel 1 complete

    #pragma unroll
    for (int q = 0; q < 4; ++q) { accL[q] = accH[q]; accH[q] = 0.f; }

    // edge (2,3): i=2 gets kc=8,ki=9 ; i=3 gets kc=10,ki=11
    edge_conv<8, 9, 10, 11, true>(sA[2], sA[3], sH[2], sH[3],
                                  ty, tx, tx4, ker, accL, accH, cA, cB);
    store_out(outp + 2 * cstride, cA, accL);         // channel 2 complete
    store_out(outp + 3 * cstride, cB, accH);         // channel 3 complete
}

__global__ __launch_bounds__(256) void bleed_kernel(
    const float* __restrict__ src,   // [4][32][512][512]
    const float* __restrict__ ker,   // [12][3][3]
    float* __restrict__ out)
{
    __shared__ __align__(16) float sA[NCH][HTH][HTW];  // a = v^(1/3), main
    __shared__ __align__(16) float sH[NCH][HTH][HSW];  // window-edge values

    const int tid    = threadIdx.x;
    const int tx     = tid & 15;      // col group: cols 4*tx .. 4*tx+3
    const int ty     = tid >> 4;      // row 0..15
    const int tx4    = tx * 4;
    const int g      = tid >> 4;      // staging task group
    const int L      = tid & 15;      // staging lane within row
    const int tile_x = blockIdx.x * TW;
    const int tile_y = blockIdx.y * TH;
    const int n0     = blockIdx.z * 2;    // this block: images n0, n0+1

    const size_t plane   = (size_t)HH * WW;
    const size_t cstride = (size_t)NIMG * plane;

    const int gy  = tile_y + ty;
    const int gx0 = tile_x + tx4;
    float* outp0 = out + (size_t)n0 * plane + (size_t)gy * WW + gx0;

    Stage s0, s1;
    stage_load(src, n0, tile_x, tile_y, g, L, plane, s0);
    stage_load(src, n0 + 1, tile_x, tile_y, g, L, plane, s1);  // prefetch
    stage_write(sA, sH, g, L, s0);      // waits s0 only (counted vmcnt)

    BAR_LDS();                          // s1 loads remain in flight

    conv_image(sA, sH, ty, tx, tx4, ker, outp0, cstride);      // image n0

    BAR_LDS();                          // all conv-1 LDS reads done

    stage_write(sA, sH, g, L, s1);      // s1 had conv-1 time to land

    BAR_LDS();

    conv_image(sA, sH, ty, tx, tx4, ker, outp0 + plane, cstride); // image n0+1
}

extern "C" void kernel_launch(void* const* d_in, const int* in_sizes, int n_in,
                              void* d_out, int out_size, void* d_ws, size_t ws_size,
                              hipStream_t stream) {
    const float* src = (const float*)d_in[0];
    const float* ker = (const float*)d_in[1];
    float* out = (float*)d_out;

    dim3 grid(WW / TW, HH / TH, NIMG / 2);   // (8, 32, 16) = 4096 blocks
    dim3 block(256);
    bleed_kernel<<<grid, block, 0, stream>>>(src, ker, out);
}

// Round 6
// 238.840 us; speedup vs baseline: 1.0562x; 1.0562x over previous
//
#include <hip/hip_runtime.h>
#include <math.h>

// sources: [4][32][512][512] fp32, kernels: [12][3][3] fp32, out: same as sources
// out_i = s_i - sum_j [ conv(s_j, kc_ij) + conv((s_j^0.5 * s_i)^(2/3), ki_ij) ]
//
// Identity: a = v^(1/3) => s = a^3, (s_j^0.5 * s_i)^(2/3) = a_j * a_i^2.
// Stage only a in LDS; conv is multiply/FMA only; edge sweep (0,1),(1,2),(2,3).
//
// ROUND-6: one image per block (round-5's 2-image pipeline REGRESSED:
// +20 VGPR, +10KB LDS -> 5 resident blocks vs 7, and the in-block serial
// chain replaced free inter-block TLP; 85->97 us). Bank-conflict fix kept
// but implemented in-place: the window-edge values w0 (col 4tx+3) and w5
// (col 4tx+8) are read as 8B-aligned ds_read_b64 (use .y / .x) instead of
// b32. b32 at 8ty+4tx+3 mod 32 hit 8 banks 8-way (the ENTIRE 1.9K
// conflict-cyc/block of round 4 -- calibrated vs m136); b64 phase groups
// (16 lanes x 8B = 128B) are 2-way aliased = free. b128 reads were already
// conflict-free (contiguous 256B per 16-lane row). No side array, no extra
// staging work, LDS unchanged.
//
// HISTORY (do not regress):
//  - launch_bounds (256,8)/(256,4): VGPR cap -> spills. WRITE_SIZE must
//    stay exactly 131072 KB; anything more is scratch traffic. Unbounded.
//  - scalar staging loads: Little's-law capped kernel at ~250 us. Keep
//    batched float4 staging (all 5 loads in flight before first use).
//  - 2 images/block + reg prefetch: net loss (see above).

#define NCH  4
#define NIMG 32
#define HH   512
#define WW   512

#define TW   64
#define TH   16
#define HTW  72            // LDS row stride (dwords); col k = global tile_x+k-4
#define HTH  18
#define NTASK (NCH * HTH)  // 72 row-channel staging tasks

#if __has_builtin(__builtin_amdgcn_exp2f)
#define EXP2(x) __builtin_amdgcn_exp2f(x)
#else
#define EXP2(x) exp2f(x)
#endif
#if __has_builtin(__builtin_amdgcn_logf)
#define LOG2(x) __builtin_amdgcn_logf(x)
#else
#define LOG2(x) __log2f(x)
#endif

__device__ __forceinline__ float cbrtfast(float v) {
    return EXP2(0.33333334f * LOG2(v));   // v=0 -> -inf -> 0 (correct zero-pad)
}

// Window = LDS cols tx4+3 .. tx4+8 (global cols tile_x+tx4-1 .. +4).
// row points at &S[y][tx4] (16B aligned).
//   w1..w4: ds_read_b128 at +4 (conflict-free).
//   w0:     ds_read_b64 at +2, take .y  (col 4tx+3; .x is dead).
//   w5:     ds_read_b64 at +8, take .x  (col 4tx+8; .y is dead).
// Cols 2 (tx=0) and 4tx+9 (tx=15) may be uninitialized LDS; their lanes'
// dead components are never used. 2-way bank alias per phase = free.
__device__ __forceinline__ void load_row6(const float* __restrict__ row, float w[6]) {
    const float4 m = *(const float4*)(row + 4);
    const float2 a = *(const float2*)(row + 2);
    const float2 b = *(const float2*)(row + 8);
    w[0] = a.y;
    w[1] = m.x; w[2] = m.y; w[3] = m.z; w[4] = m.w;
    w[5] = b.x;
}

// Edge between channels x and y = x+1 (a-values in Sx, Sy).
//   accX += conv(a_y^3, ker[KCX]) + conv(a_x^2 * a_y, ker[KIX])   (i=x, j=y)
//   accY += conv(a_x^3, ker[KCY]) + conv(a_y^2 * a_x, ker[KIY])   (i=y, j=x)
template<int KCX, int KIX, int KCY, int KIY, bool CAPY>
__device__ __forceinline__ void edge_conv(
    const float (*Sx)[HTW], const float (*Sy)[HTW],
    int ty, int tx4, const float* __restrict__ ker,
    float accX[4], float accY[4], float cx[4], float cy[4])
{
    #pragma unroll
    for (int r = 0; r < 3; ++r) {
        float ax[6], ay[6];
        load_row6(&Sx[ty + r][tx4], ax);
        load_row6(&Sy[ty + r][tx4], ay);
        if (r == 1) {
            #pragma unroll
            for (int q = 0; q < 4; ++q) cx[q] = ax[q + 1];
            if (CAPY) {
                #pragma unroll
                for (int q = 0; q < 4; ++q) cy[q] = ay[q + 1];
            }
        }
        float ay2[6];
        #pragma unroll
        for (int q = 0; q < 6; ++q) ay2[q] = ay[q] * ay[q];

        // i=x (neighbor j=y): raw_y = ay^3, inter = ax^2 * ay
        {
            float w[6], t[6];
            #pragma unroll
            for (int q = 0; q < 6; ++q) {
                w[q] = ay2[q] * ay[q];
                t[q] = (ax[q] * ax[q]) * ay[q];
            }
            #pragma unroll
            for (int q = 0; q < 4; ++q) {
                float s = accX[q];
                #pragma unroll
                for (int dx = 0; dx < 3; ++dx) {
                    s = fmaf(w[q + dx], ker[KCX * 9 + r * 3 + dx], s);
                    s = fmaf(t[q + dx], ker[KIX * 9 + r * 3 + dx], s);
                }
                accX[q] = s;
            }
        }
        // i=y (neighbor j=x): raw_x = ax^3, inter = ay^2 * ax
        {
            float w[6], t[6];
            #pragma unroll
            for (int q = 0; q < 6; ++q) {
                w[q] = (ax[q] * ax[q]) * ax[q];
                t[q] = ay2[q] * ax[q];
            }
            #pragma unroll
            for (int q = 0; q < 4; ++q) {
                float s = accY[q];
                #pragma unroll
                for (int dx = 0; dx < 3; ++dx) {
                    s = fmaf(w[q + dx], ker[KCY * 9 + r * 3 + dx], s);
                    s = fmaf(t[q + dx], ker[KIY * 9 + r * 3 + dx], s);
                }
                accY[q] = s;
            }
        }
    }
}

__device__ __forceinline__ void store_out(float* __restrict__ p,
                                          const float c[4], const float a[4]) {
    float4 o;
    o.x = c[0] * c[0] * c[0] - a[0];
    o.y = c[1] * c[1] * c[1] - a[1];
    o.z = c[2] * c[2] * c[2] - a[2];
    o.w = c[3] * c[3] * c[3] - a[3];
    *(float4*)p = o;
}

__global__ __launch_bounds__(256) void bleed_kernel(
    const float* __restrict__ src,   // [4][32][512][512]
    const float* __restrict__ ker,   // [12][3][3]
    float* __restrict__ out)
{
    __shared__ __align__(16) float sA[NCH][HTH][HTW];  // a = v^(1/3)

    const int tid    = threadIdx.x;
    const int tx     = tid & 15;      // col group: cols 4*tx .. 4*tx+3
    const int ty     = tid >> 4;      // row 0..15
    const int tx4    = tx * 4;
    const int tile_x = blockIdx.x * TW;
    const int tile_y = blockIdx.y * TH;
    const int n      = blockIdx.z;    // image index

    const size_t plane = (size_t)HH * WW;

    // ---- stage a = v^(1/3), zero-padded halo; float4 loads, batched ----
    // 16 groups of 16 lanes; task t = (channel c = t/18, row = t%18).
    // Lane L loads float4 of global cols tile_x+4L..+3 -> LDS cols 4+4L..7+4L.
    // Lane 0 also loads left halo (-> LDS col 3), lane 1 right halo (-> col
    // 68). All 5 tasks' loads issued before any use (bytes-in-flight).
    {
        const int g = tid >> 4;
        const int L = tid & 15;
        float4 vv[5];
        float  hv[5];
        #pragma unroll
        for (int it = 0; it < 5; ++it) {
            const int t   = g + it * 16;
            const int c   = t / HTH;
            const int row = t - c * HTH;
            const int gy  = tile_y - 1 + row;
            float4 v = make_float4(0.f, 0.f, 0.f, 0.f);
            float  h = 0.f;
            if (t < NTASK && (unsigned)gy < HH) {
                const float* rp = src + ((size_t)c * NIMG + n) * plane
                                      + (size_t)gy * WW;
                v = *(const float4*)(rp + tile_x + 4 * L);
                if (L == 0 && tile_x > 0)       h = rp[tile_x - 1];
                if (L == 1 && tile_x + TW < WW) h = rp[tile_x + TW];
            }
            vv[it] = v;
            hv[it] = h;
        }
        #pragma unroll
        for (int it = 0; it < 5; ++it) {
            const int t = g + it * 16;
            if (t < NTASK) {
                const int c   = t / HTH;
                const int row = t - c * HTH;
                float4 a;
                a.x = cbrtfast(vv[it].x);
                a.y = cbrtfast(vv[it].y);
                a.z = cbrtfast(vv[it].z);
                a.w = cbrtfast(vv[it].w);
                const float ah = cbrtfast(hv[it]);
                *(float4*)&sA[c][row][4 + 4 * L] = a;    // 16B-aligned ds_write
                if (L == 0) sA[c][row][3]  = ah;
                if (L == 1) sA[c][row][68] = ah;
            }
        }
    }
    __syncthreads();   // only barrier: everything after is read-only LDS

    const int gy  = tile_y + ty;
    const int gx0 = tile_x + tx4;
    float* outp = out + (size_t)n * plane + (size_t)gy * WW + gx0;
    const size_t cstride = (size_t)NIMG * plane;

    float accL[4] = {0.f, 0.f, 0.f, 0.f};
    float accH[4] = {0.f, 0.f, 0.f, 0.f};
    float cA[4], cB[4];

    // edge (0,1): i=0 gets kc=0,ki=1 ; i=1 gets kc=2,ki=3
    edge_conv<0, 1, 2, 3, false>(sA[0], sA[1], ty, tx4, ker, accL, accH, cA, cB);
    store_out(outp, cA, accL);                       // channel 0 complete

    #pragma unroll
    for (int q = 0; q < 4; ++q) { accL[q] = accH[q]; accH[q] = 0.f; }

    // edge (1,2): i=1 gets kc=4,ki=5 ; i=2 gets kc=6,ki=7
    edge_conv<4, 5, 6, 7, false>(sA[1], sA[2], ty, tx4, ker, accL, accH, cA, cB);
    store_out(outp + cstride, cA, accL);             // channel 1 complete

    #pragma unroll
    for (int q = 0; q < 4; ++q) { accL[q] = accH[q]; accH[q] = 0.f; }

    // edge (2,3): i=2 gets kc=8,ki=9 ; i=3 gets kc=10,ki=11
    edge_conv<8, 9, 10, 11, true>(sA[2], sA[3], ty, tx4, ker, accL, accH, cA, cB);
    store_out(outp + 2 * cstride, cA, accL);         // channel 2 complete
    store_out(outp + 3 * cstride, cB, accH);         // channel 3 complete
}

extern "C" void kernel_launch(void* const* d_in, const int* in_sizes, int n_in,
                              void* d_out, int out_size, void* d_ws, size_t ws_size,
                              hipStream_t stream) {
    const float* src = (const float*)d_in[0];
    const float* ker = (const float*)d_in[1];
    float* out = (float*)d_out;

    dim3 grid(WW / TW, HH / TH, NIMG);   // (8, 32, 32) = 8192 blocks
    dim3 block(256);
    bleed_kernel<<<grid, block, 0, stream>>>(src, ker, out);
}